// Round 13
// baseline (431.788 us; speedup 1.0000x reference)
//
#include <hip/hip_runtime.h>
#include <hip/hip_bf16.h>

#define B_  32
#define S_  4096
#define H_  1024
#define NH_ 16
#define DK_ 64
#define NCH 16                            // chunks of 256 rows
#define ROWS 256
#define TILE 2                            // rows per register tile
#define NT (ROWS / TILE)                  // 128 tiles per chunk

// workspace layout (float offsets)
#define Q_OFF  0
#define T_OFF  (Q_OFF + B_*H_)            // q: B*H
#define YP_OFF (T_OFF + B_*NH_*H_)        // t: B*NH*H
#define ML_OFF (YP_OFF + NCH*B_*NH_*H_)   // y_part: NCH*B*NH*H (32 MB)
#define Y2_OFF (ML_OFF + NCH*B_*2*NH_)    // ml stats
#define OP_OFF (Y2_OFF + B_*NH_*H_)       // reduced y: B*NH*H

#define DOT4(a, v) ((a).x*(v).x + (a).y*(v).y + (a).z*(v).z + (a).w*(v).w)

// butterfly-add via DPP (VALU pipe). 0xB1=xor1, 0x4E=xor2,
// 0x141=row_half_mirror (xor4), 0x140=row_mirror (xor8).
template <int CTRL>
__device__ __forceinline__ float dppadd(float v) {
  int mv = __builtin_amdgcn_update_dpp(0, __float_as_int(v), CTRL, 0xF, 0xF, true);
  return v + __int_as_float(mv);
}

// ---------------- kernel 1: q[b,i] = x[b,S-1,:] . Wq[i,:] + bq[i] ----------
__global__ __launch_bounds__(256) void k_q(const float* __restrict__ x,
                                           const float* __restrict__ Wq,
                                           const float* __restrict__ bq,
                                           float* __restrict__ q) {
  __shared__ __align__(16) float xl[4 * H_];
  int islab = blockIdx.x, bg = blockIdx.y, tid = threadIdx.x;
  #pragma unroll
  for (int k = 0; k < 4; ++k) {
    int idx4 = k * 256 + tid;
    int bl = idx4 >> 8, col4 = idx4 & 255;
    *(float4*)&xl[bl * H_ + col4 * 4] =
        *(const float4*)(x + (((size_t)(bg * 4 + bl)) * S_ + (S_ - 1)) * H_ + col4 * 4);
  }
  __syncthreads();
  int d = tid >> 2, p = tid & 3;
  int i = islab * 64 + d;
  const float* w = Wq + (size_t)i * H_ + p * 256;
  float acc[4] = {0.f, 0.f, 0.f, 0.f};
  #pragma unroll 4
  for (int jj = 0; jj < 256; jj += 4) {
    float4 wv = *(const float4*)(w + jj);
    #pragma unroll
    for (int bl = 0; bl < 4; ++bl) {
      float4 xv = *(const float4*)&xl[bl * H_ + p * 256 + jj];
      acc[bl] += DOT4(xv, wv);
    }
  }
  #pragma unroll
  for (int bl = 0; bl < 4; ++bl) {
    acc[bl] += __shfl_xor(acc[bl], 1);
    acc[bl] += __shfl_xor(acc[bl], 2);
  }
  if (p == 0) {
    float bias = bq[i];
    #pragma unroll
    for (int bl = 0; bl < 4; ++bl)
      q[(size_t)(bg * 4 + bl) * H_ + i] = acc[bl] + bias;
  }
}

// -------- kernel 2: t[b,h,j] = sum_d q[b,h,d]*Wk[h*64+d, j] ---------------
// (the q.bk bias term is softmax-invariant -> dropped entirely)
__global__ __launch_bounds__(256) void k_t(const float* __restrict__ q,
                                           const float* __restrict__ Wk,
                                           float* __restrict__ t) {
  __shared__ __align__(16) float qh[B_ * DK_];   // 8 KB
  int js = blockIdx.x, h = blockIdx.y, tid = threadIdx.x;
  #pragma unroll
  for (int k = 0; k < 2; ++k) {
    int idx4 = k * 256 + tid;
    int bl = idx4 >> 4, d4 = idx4 & 15;
    *(float4*)&qh[bl * DK_ + d4 * 4] =
        *(const float4*)(q + (size_t)bl * H_ + h * DK_ + d4 * 4);
  }
  __syncthreads();

  int bh = tid >> 7;                    // batch half: 0 or 1
  int j = js * 128 + (tid & 127);
  float acc[16];
  #pragma unroll
  for (int bl = 0; bl < 16; ++bl) acc[bl] = 0.f;
  for (int d = 0; d < DK_; ++d) {
    float wv = Wk[((size_t)(h * DK_ + d)) * H_ + j];
    #pragma unroll
    for (int bl = 0; bl < 16; ++bl) acc[bl] += qh[(bh * 16 + bl) * DK_ + d] * wv;
  }
  #pragma unroll
  for (int bl = 0; bl < 16; ++bl)
    t[((size_t)((bh * 16 + bl) * NH_ + h)) * H_ + j] = acc[bl];
}

// ---- kernel 3 (fused flash pass, all-register, zero LDS/barriers, explicit
// TILE=2 ping-pong prefetch): 256 thr = 4 waves x 4 heads each. Lane owns
// cols ln*16..+15. Register budget: tf 64 + ya 64 + xa 32 + xb 32 + temps
// ~= 230 regs -> needs the 256 tier; __launch_bounds__(256,1) grants the
// full budget (256-thr blocks are NOT hard-capped like 512-thr ones).
__global__ __launch_bounds__(256, 1) void k_flash(const float* __restrict__ x,
                                                  const float* __restrict__ t,
                                                  float* __restrict__ ypart,
                                                  float* __restrict__ mlpart) {
  int ch = blockIdx.x, b = blockIdx.y, tid = threadIdx.x;
  int wv = tid >> 6, ln = tid & 63;

  const float* xg = x + ((size_t)b * S_ + (size_t)ch * ROWS) * H_ + ln * 16;

  // t fragments: wave's 4 heads, lane's 16 cols
  float4 tf[4][4];
  #pragma unroll
  for (int hh = 0; hh < 4; ++hh) {
    const float* tg = t + ((size_t)b * NH_ + wv * 4 + hh) * H_ + ln * 16;
    #pragma unroll
    for (int j = 0; j < 4; ++j) tf[hh][j] = *(const float4*)(tg + j * 4);
  }

  float4 ya[4][4];
  #pragma unroll
  for (int hh = 0; hh < 4; ++hh)
    #pragma unroll
    for (int j = 0; j < 4; ++j) {
      ya[hh][j].x = 0.f; ya[hh][j].y = 0.f; ya[hh][j].z = 0.f; ya[hh][j].w = 0.f;
    }
  float m_r[4] = {-3.4e38f, -3.4e38f, -3.4e38f, -3.4e38f};
  float l_r[4] = {0.f, 0.f, 0.f, 0.f};

  float4 xa[TILE][4], xb[TILE][4];

#define LOADX(dst, tl)                                                        \
  {                                                                           \
    _Pragma("unroll") for (int s_ = 0; s_ < TILE; ++s_) {                     \
      const float* xrow_ = xg + (size_t)((tl) * TILE + s_) * H_;              \
      _Pragma("unroll") for (int j_ = 0; j_ < 4; ++j_)                        \
          dst[s_][j_] = *(const float4*)(xrow_ + j_ * 4);                     \
    }                                                                         \
  }

#define COMPUTE(src)                                                          \
  {                                                                           \
    float scr[4][TILE];                                                       \
    _Pragma("unroll") for (int hh = 0; hh < 4; ++hh)                          \
      _Pragma("unroll") for (int s = 0; s < TILE; ++s) {                      \
        float a = DOT4(src[s][0], tf[hh][0]);                                 \
        a += DOT4(src[s][1], tf[hh][1]);                                      \
        a += DOT4(src[s][2], tf[hh][2]);                                      \
        a += DOT4(src[s][3], tf[hh][3]);                                      \
        scr[hh][s] = a;                                                       \
      }                                                                       \
    _Pragma("unroll") for (int hh = 0; hh < 4; ++hh)                          \
      _Pragma("unroll") for (int s = 0; s < TILE; ++s) {                      \
        float a = scr[hh][s];                                                 \
        a = dppadd<0xB1>(a);                                                  \
        a = dppadd<0x4E>(a);                                                  \
        a = dppadd<0x141>(a);                                                 \
        a = dppadd<0x140>(a);                                                 \
        a += __shfl_xor(a, 16);                                               \
        a += __shfl_xor(a, 32);                                               \
        scr[hh][s] = a * 0.125f;                                              \
      }                                                                       \
    _Pragma("unroll") for (int hh = 0; hh < 4; ++hh) {                        \
      float tmax = fmaxf(scr[hh][0], scr[hh][1]);                             \
      float mnew = fmaxf(m_r[hh], tmax);                                      \
      float fac = __expf(m_r[hh] - mnew);                                     \
      float e0 = __expf(scr[hh][0] - mnew);                                   \
      float e1 = __expf(scr[hh][1] - mnew);                                   \
      m_r[hh] = mnew;                                                         \
      l_r[hh] = l_r[hh] * fac + (e0 + e1);                                    \
      _Pragma("unroll") for (int j = 0; j < 4; ++j) {                         \
        float4 y0 = ya[hh][j];                                                \
        y0.x = y0.x * fac + e0 * src[0][j].x + e1 * src[1][j].x;              \
        y0.y = y0.y * fac + e0 * src[0][j].y + e1 * src[1][j].y;              \
        y0.z = y0.z * fac + e0 * src[0][j].z + e1 * src[1][j].z;              \
        y0.w = y0.w * fac + e0 * src[0][j].w + e1 * src[1][j].w;              \
        ya[hh][j] = y0;                                                       \
      }                                                                       \
    }                                                                         \
  }

  // prologue: tile 0 -> xa
  LOADX(xa, 0);
  #pragma unroll 1
  for (int u = 0; u < NT; u += 2) {
    LOADX(xb, u + 1);                       // NT even: u+1 <= NT-1 always
    COMPUTE(xa);
    int t2 = (u + 2 < NT) ? u + 2 : 0;      // clamped redundant load at tail
    LOADX(xa, t2);
    COMPUTE(xb);
  }
#undef LOADX
#undef COMPUTE

  // epilogue: lane owns (4 heads, cols ln*16..+15)
  float* yo = ypart + ((size_t)(ch * B_ + b)) * NH_ * H_ + ln * 16;
  #pragma unroll
  for (int hh = 0; hh < 4; ++hh)
    #pragma unroll
    for (int j = 0; j < 4; ++j)
      *(float4*)(yo + (size_t)(wv * 4 + hh) * H_ + j * 4) = ya[hh][j];
  if (ln == 0) {
    #pragma unroll
    for (int hh = 0; hh < 4; ++hh) {
      size_t base = ((size_t)(ch * B_ + b)) * (2 * NH_) + (size_t)(wv * 4 + hh) * 2;
      mlpart[base + 0] = m_r[hh];
      mlpart[base + 1] = l_r[hh];
    }
  }
}

// ---- kernel 4: y2[b,h,:] = (sum_ch w_ch * y_part[ch]) / L  (512 blocks) ---
__global__ __launch_bounds__(256) void k_yred(const float* __restrict__ ypart,
                                              const float* __restrict__ mlpart,
                                              float* __restrict__ y2) {
  int h = blockIdx.x, b = blockIdx.y, tid = threadIdx.x;
  float mg = -3.4e38f;
  for (int ch = 0; ch < NCH; ++ch)
    mg = fmaxf(mg, mlpart[((size_t)(ch * B_ + b)) * (2 * NH_) + h * 2]);
  float L = 0.f;
  float4 acc; acc.x = acc.y = acc.z = acc.w = 0.f;
  for (int ch = 0; ch < NCH; ++ch) {
    float mc = mlpart[((size_t)(ch * B_ + b)) * (2 * NH_) + h * 2 + 0];
    float lc = mlpart[((size_t)(ch * B_ + b)) * (2 * NH_) + h * 2 + 1];
    float w = __expf(mc - mg);
    L += w * lc;
    float4 v = *(const float4*)(ypart +
        ((size_t)(ch * B_ + b)) * NH_ * H_ + (size_t)h * H_ + tid * 4);
    acc.x += w * v.x; acc.y += w * v.y; acc.z += w * v.z; acc.w += w * v.w;
  }
  float inv = 1.f / L;
  acc.x *= inv; acc.y *= inv; acc.z *= inv; acc.w *= inv;
  *(float4*)(y2 + ((size_t)(b * NH_ + h)) * H_ + tid * 4) = acc;
}

// -------- kernel 5: op[b,h*64+d] = Wv[h*64+d,:].y2[b,h,:] + bv -------------
__global__ __launch_bounds__(256) void k_vproj(const float* __restrict__ y2,
                                               const float* __restrict__ Wv,
                                               const float* __restrict__ bv,
                                               float* __restrict__ op) {
  __shared__ __align__(16) float yl[4 * H_];
  int h = blockIdx.x, bg = blockIdx.y, tid = threadIdx.x;
  #pragma unroll
  for (int k = 0; k < 4; ++k) {
    int idx4 = k * 256 + tid;
    int bl = idx4 >> 8, col4 = idx4 & 255;
    *(float4*)&yl[bl * H_ + col4 * 4] =
        *(const float4*)(y2 + ((size_t)((bg * 4 + bl) * NH_ + h)) * H_ + col4 * 4);
  }
  __syncthreads();
  int d = tid >> 2, p = tid & 3;
  const float* w = Wv + ((size_t)(h * DK_ + d)) * H_ + p * 256;
  float acc[4] = {0.f, 0.f, 0.f, 0.f};
  #pragma unroll 4
  for (int jj = 0; jj < 256; jj += 4) {
    float4 wv = *(const float4*)(w + jj);
    #pragma unroll
    for (int bl = 0; bl < 4; ++bl) {
      float4 yv = *(const float4*)&yl[bl * H_ + p * 256 + jj];
      acc[bl] += DOT4(yv, wv);
    }
  }
  #pragma unroll
  for (int bl = 0; bl < 4; ++bl) {
    acc[bl] += __shfl_xor(acc[bl], 1);
    acc[bl] += __shfl_xor(acc[bl], 2);
  }
  if (p == 0) {
    float bias = bv[h * DK_ + d];
    #pragma unroll
    for (int bl = 0; bl < 4; ++bl)
      op[(size_t)(bg * 4 + bl) * H_ + h * DK_ + d] = acc[bl] + bias;
  }
}

// -------- kernel 6: out[b,i] = Wo[i,:].out_pre[b,:] + bo[i] ----------------
__global__ __launch_bounds__(256) void k_out(const float* __restrict__ op,
                                             const float* __restrict__ Wo,
                                             const float* __restrict__ bo,
                                             float* __restrict__ out) {
  __shared__ __align__(16) float ul[4 * H_];
  int islab = blockIdx.x, bg = blockIdx.y, tid = threadIdx.x;
  #pragma unroll
  for (int k = 0; k < 4; ++k) {
    int idx4 = k * 256 + tid;
    int bl = idx4 >> 8, col4 = idx4 & 255;
    *(float4*)&ul[bl * H_ + col4 * 4] =
        *(const float4*)(op + (size_t)(bg * 4 + bl) * H_ + col4 * 4);
  }
  __syncthreads();
  int d = tid >> 2, p = tid & 3;
  int i = islab * 64 + d;
  const float* w = Wo + (size_t)i * H_ + p * 256;
  float acc[4] = {0.f, 0.f, 0.f, 0.f};
  #pragma unroll 4
  for (int jj = 0; jj < 256; jj += 4) {
    float4 wv = *(const float4*)(w + jj);
    #pragma unroll
    for (int bl = 0; bl < 4; ++bl) {
      float4 uv = *(const float4*)&ul[bl * H_ + p * 256 + jj];
      acc[bl] += DOT4(uv, wv);
    }
  }
  #pragma unroll
  for (int bl = 0; bl < 4; ++bl) {
    acc[bl] += __shfl_xor(acc[bl], 1);
    acc[bl] += __shfl_xor(acc[bl], 2);
  }
  if (p == 0) {
    float bias = bo[i];
    #pragma unroll
    for (int bl = 0; bl < 4; ++bl)
      out[(size_t)(bg * 4 + bl) * H_ + i] = acc[bl] + bias;
  }
}

extern "C" void kernel_launch(void* const* d_in, const int* in_sizes, int n_in,
                              void* d_out, int out_size, void* d_ws, size_t ws_size,
                              hipStream_t stream) {
  const float* x  = (const float*)d_in[0];
  const float* Wq = (const float*)d_in[1];
  const float* bq = (const float*)d_in[2];
  const float* Wk = (const float*)d_in[3];
  const float* Wv = (const float*)d_in[5];
  const float* bv = (const float*)d_in[6];
  const float* Wo = (const float*)d_in[7];
  const float* bo = (const float*)d_in[8];
  float* out = (float*)d_out;
  float* ws = (float*)d_ws;

  float* q  = ws + Q_OFF;
  float* t  = ws + T_OFF;
  float* yp = ws + YP_OFF;
  float* ml = ws + ML_OFF;
  float* y2 = ws + Y2_OFF;
  float* op = ws + OP_OFF;

  k_q<<<dim3(16, B_ / 4), 256, 0, stream>>>(x, Wq, bq, q);
  k_t<<<dim3(8, NH_), 256, 0, stream>>>(q, Wk, t);
  k_flash<<<dim3(NCH, B_), 256, 0, stream>>>(x, t, yp, ml);
  k_yred<<<dim3(NH_, B_), 256, 0, stream>>>(yp, ml, y2);
  k_vproj<<<dim3(NH_, B_ / 4), 256, 0, stream>>>(y2, Wv, bv, op);
  k_out<<<dim3(16, B_ / 4), 256, 0, stream>>>(op, Wo, bo, out);
}

// Round 14
// 272.975 us; speedup vs baseline: 1.5818x; 1.5818x over previous
//
#include <hip/hip_runtime.h>
#include <hip/hip_bf16.h>

#define B_  32
#define S_  4096
#define H_  1024
#define NH_ 16
#define DK_ 64
#define NCH 32                            // chunks of 128 rows
#define ROWS 128
#define TILE 4                            // rows per register tile
#define NT (ROWS / TILE)                  // 32 tiles per chunk

// workspace layout (float offsets)
#define Q_OFF  0
#define T_OFF  (Q_OFF + B_*H_)            // q: B*H
#define YP_OFF (T_OFF + B_*NH_*H_)        // t: B*NH*H
#define ML_OFF (YP_OFF + NCH*B_*NH_*H_)   // y_part: NCH*B*NH*H (64 MB)
#define Y2_OFF (ML_OFF + NCH*B_*2*NH_)    // ml stats
#define OP_OFF (Y2_OFF + B_*NH_*H_)       // reduced y: B*NH*H

#define DOT4(a, v) ((a).x*(v).x + (a).y*(v).y + (a).z*(v).z + (a).w*(v).w)

typedef float v2f __attribute__((ext_vector_type(2)));
struct alignas(16) F4 { v2f lo, hi; };    // 4 floats as two packed pairs

__device__ __forceinline__ v2f v2z() { v2f z; z.x = 0.f; z.y = 0.f; return z; }

// butterfly-add via DPP (VALU pipe). 0xB1=xor1, 0x4E=xor2,
// 0x141=row_half_mirror (xor4), 0x140=row_mirror (xor8).
template <int CTRL>
__device__ __forceinline__ float dppadd(float v) {
  int mv = __builtin_amdgcn_update_dpp(0, __float_as_int(v), CTRL, 0xF, 0xF, true);
  return v + __int_as_float(mv);
}

// ---------------- kernel 1: q[b,i] = x[b,S-1,:] . Wq[i,:] + bq[i] ----------
__global__ __launch_bounds__(256) void k_q(const float* __restrict__ x,
                                           const float* __restrict__ Wq,
                                           const float* __restrict__ bq,
                                           float* __restrict__ q) {
  __shared__ __align__(16) float xl[4 * H_];
  int islab = blockIdx.x, bg = blockIdx.y, tid = threadIdx.x;
  #pragma unroll
  for (int k = 0; k < 4; ++k) {
    int idx4 = k * 256 + tid;
    int bl = idx4 >> 8, col4 = idx4 & 255;
    *(float4*)&xl[bl * H_ + col4 * 4] =
        *(const float4*)(x + (((size_t)(bg * 4 + bl)) * S_ + (S_ - 1)) * H_ + col4 * 4);
  }
  __syncthreads();
  int d = tid >> 2, p = tid & 3;
  int i = islab * 64 + d;
  const float* w = Wq + (size_t)i * H_ + p * 256;
  float acc[4] = {0.f, 0.f, 0.f, 0.f};
  #pragma unroll 4
  for (int jj = 0; jj < 256; jj += 4) {
    float4 wv = *(const float4*)(w + jj);
    #pragma unroll
    for (int bl = 0; bl < 4; ++bl) {
      float4 xv = *(const float4*)&xl[bl * H_ + p * 256 + jj];
      acc[bl] += DOT4(xv, wv);
    }
  }
  #pragma unroll
  for (int bl = 0; bl < 4; ++bl) {
    acc[bl] += __shfl_xor(acc[bl], 1);
    acc[bl] += __shfl_xor(acc[bl], 2);
  }
  if (p == 0) {
    float bias = bq[i];
    #pragma unroll
    for (int bl = 0; bl < 4; ++bl)
      q[(size_t)(bg * 4 + bl) * H_ + i] = acc[bl] + bias;
  }
}

// -------- kernel 2: t[b,h,j] = sum_d q[b,h,d]*Wk[h*64+d, j] ---------------
// (the q.bk bias term is softmax-invariant -> dropped entirely)
__global__ __launch_bounds__(256) void k_t(const float* __restrict__ q,
                                           const float* __restrict__ Wk,
                                           float* __restrict__ t) {
  __shared__ __align__(16) float qh[B_ * DK_];   // 8 KB
  int js = blockIdx.x, h = blockIdx.y, tid = threadIdx.x;
  #pragma unroll
  for (int k = 0; k < 2; ++k) {
    int idx4 = k * 256 + tid;
    int bl = idx4 >> 4, d4 = idx4 & 15;
    *(float4*)&qh[bl * DK_ + d4 * 4] =
        *(const float4*)(q + (size_t)bl * H_ + h * DK_ + d4 * 4);
  }
  __syncthreads();

  int bh = tid >> 7;                    // batch half: 0 or 1
  int j = js * 128 + (tid & 127);
  float acc[16];
  #pragma unroll
  for (int bl = 0; bl < 16; ++bl) acc[bl] = 0.f;
  for (int d = 0; d < DK_; ++d) {
    float wv = Wk[((size_t)(h * DK_ + d)) * H_ + j];
    #pragma unroll
    for (int bl = 0; bl < 16; ++bl) acc[bl] += qh[(bh * 16 + bl) * DK_ + d] * wv;
  }
  #pragma unroll
  for (int bl = 0; bl < 16; ++bl)
    t[((size_t)((bh * 16 + bl) * NH_ + h)) * H_ + j] = acc[bl];
}

// ---- kernel 3 (fused flash pass, all-register, zero LDS/barriers; R10
// structure + PACKED fp32 math): 256 thr = 4 waves x 4 heads. Lane owns
// cols ln*16..+15. Phase-A dots and phase-B accumulates on v2f pairs ->
// v_pk_fma_f32 (2 FLOP-pairs/instr), ~1.5x fewer VALU instructions.
__global__ __launch_bounds__(256) void k_flash(const float* __restrict__ x,
                                               const float* __restrict__ t,
                                               float* __restrict__ ypart,
                                               float* __restrict__ mlpart) {
  int ch = blockIdx.x, b = blockIdx.y, tid = threadIdx.x;
  int wv = tid >> 6, ln = tid & 63;

  const float* xg = x + ((size_t)b * S_ + (size_t)ch * ROWS) * H_ + ln * 16;

  // t fragments: wave's 4 heads, lane's 16 cols
  F4 tf[4][4];
  #pragma unroll
  for (int hh = 0; hh < 4; ++hh) {
    const float* tg = t + ((size_t)b * NH_ + wv * 4 + hh) * H_ + ln * 16;
    #pragma unroll
    for (int j = 0; j < 4; ++j)
      *(float4*)&tf[hh][j] = *(const float4*)(tg + j * 4);
  }

  F4 ya[4][4];
  #pragma unroll
  for (int hh = 0; hh < 4; ++hh)
    #pragma unroll
    for (int j = 0; j < 4; ++j) { ya[hh][j].lo = v2z(); ya[hh][j].hi = v2z(); }
  float m_r[4] = {-3.4e38f, -3.4e38f, -3.4e38f, -3.4e38f};
  float l_r[4] = {0.f, 0.f, 0.f, 0.f};

  #pragma unroll 1
  for (int u = 0; u < NT; ++u) {
    // x fragment: 4 rows x 64B/lane, coalesced; feeds BOTH phases from regs
    F4 xr[TILE][4];
    #pragma unroll
    for (int s = 0; s < TILE; ++s) {
      const float* xrow = xg + (size_t)(u * TILE + s) * H_;
      #pragma unroll
      for (int j = 0; j < 4; ++j)
        *(float4*)&xr[s][j] = *(const float4*)(xrow + j * 4);
    }

    // phase A: packed partial dots (lane's 16 cols) for 4 heads x 4 rows
    float scr[4][TILE];
    #pragma unroll
    for (int hh = 0; hh < 4; ++hh)
      #pragma unroll
      for (int s = 0; s < TILE; ++s) {
        v2f a2 = xr[s][0].lo * tf[hh][0].lo;
        a2 += xr[s][0].hi * tf[hh][0].hi;
        a2 += xr[s][1].lo * tf[hh][1].lo;
        a2 += xr[s][1].hi * tf[hh][1].hi;
        a2 += xr[s][2].lo * tf[hh][2].lo;
        a2 += xr[s][2].hi * tf[hh][2].hi;
        a2 += xr[s][3].lo * tf[hh][3].lo;
        a2 += xr[s][3].hi * tf[hh][3].hi;
        scr[hh][s] = a2.x + a2.y;
      }

    // 64-lane butterfly reduce: every lane ends with the full dot
    #pragma unroll
    for (int hh = 0; hh < 4; ++hh)
      #pragma unroll
      for (int s = 0; s < TILE; ++s) {
        float a = scr[hh][s];
        a = dppadd<0xB1>(a);    // xor1
        a = dppadd<0x4E>(a);    // xor2
        a = dppadd<0x141>(a);   // xor4 (row_half_mirror)
        a = dppadd<0x140>(a);   // xor8 (row_mirror)
        a += __shfl_xor(a, 16);
        a += __shfl_xor(a, 32);
        scr[hh][s] = a * 0.125f;
      }

    // in-register online softmax + packed PV accumulation per head
    #pragma unroll
    for (int hh = 0; hh < 4; ++hh) {
      float tmax = fmaxf(fmaxf(scr[hh][0], scr[hh][1]), fmaxf(scr[hh][2], scr[hh][3]));
      float mnew = fmaxf(m_r[hh], tmax);
      float fac = __expf(m_r[hh] - mnew);
      float e0 = __expf(scr[hh][0] - mnew);
      float e1 = __expf(scr[hh][1] - mnew);
      float e2 = __expf(scr[hh][2] - mnew);
      float e3 = __expf(scr[hh][3] - mnew);
      m_r[hh] = mnew;
      l_r[hh] = l_r[hh] * fac + (e0 + e1 + e2 + e3);
      #pragma unroll
      for (int j = 0; j < 4; ++j) {
        v2f lo = ya[hh][j].lo * fac;
        lo += e0 * xr[0][j].lo;
        lo += e1 * xr[1][j].lo;
        lo += e2 * xr[2][j].lo;
        lo += e3 * xr[3][j].lo;
        ya[hh][j].lo = lo;
        v2f hi = ya[hh][j].hi * fac;
        hi += e0 * xr[0][j].hi;
        hi += e1 * xr[1][j].hi;
        hi += e2 * xr[2][j].hi;
        hi += e3 * xr[3][j].hi;
        ya[hh][j].hi = hi;
      }
    }
  }

  // epilogue: lane owns (4 heads, cols ln*16..+15)
  float* yo = ypart + ((size_t)(ch * B_ + b)) * NH_ * H_ + ln * 16;
  #pragma unroll
  for (int hh = 0; hh < 4; ++hh)
    #pragma unroll
    for (int j = 0; j < 4; ++j)
      *(F4*)(yo + (size_t)(wv * 4 + hh) * H_ + j * 4) = ya[hh][j];
  if (ln == 0) {
    #pragma unroll
    for (int hh = 0; hh < 4; ++hh) {
      size_t base = ((size_t)(ch * B_ + b)) * (2 * NH_) + (size_t)(wv * 4 + hh) * 2;
      mlpart[base + 0] = m_r[hh];
      mlpart[base + 1] = l_r[hh];
    }
  }
}

// ---- kernel 4: y2[b,h,:] = (sum_ch w_ch * y_part[ch]) / L  (512 blocks) ---
__global__ __launch_bounds__(256) void k_yred(const float* __restrict__ ypart,
                                              const float* __restrict__ mlpart,
                                              float* __restrict__ y2) {
  int h = blockIdx.x, b = blockIdx.y, tid = threadIdx.x;
  float mg = -3.4e38f;
  for (int ch = 0; ch < NCH; ++ch)
    mg = fmaxf(mg, mlpart[((size_t)(ch * B_ + b)) * (2 * NH_) + h * 2]);
  float L = 0.f;
  float4 acc; acc.x = acc.y = acc.z = acc.w = 0.f;
  for (int ch = 0; ch < NCH; ++ch) {
    float mc = mlpart[((size_t)(ch * B_ + b)) * (2 * NH_) + h * 2 + 0];
    float lc = mlpart[((size_t)(ch * B_ + b)) * (2 * NH_) + h * 2 + 1];
    float w = __expf(mc - mg);
    L += w * lc;
    float4 v = *(const float4*)(ypart +
        ((size_t)(ch * B_ + b)) * NH_ * H_ + (size_t)h * H_ + tid * 4);
    acc.x += w * v.x; acc.y += w * v.y; acc.z += w * v.z; acc.w += w * v.w;
  }
  float inv = 1.f / L;
  acc.x *= inv; acc.y *= inv; acc.z *= inv; acc.w *= inv;
  *(float4*)(y2 + ((size_t)(b * NH_ + h)) * H_ + tid * 4) = acc;
}

// -------- kernel 5: op[b,h*64+d] = Wv[h*64+d,:].y2[b,h,:] + bv -------------
__global__ __launch_bounds__(256) void k_vproj(const float* __restrict__ y2,
                                               const float* __restrict__ Wv,
                                               const float* __restrict__ bv,
                                               float* __restrict__ op) {
  __shared__ __align__(16) float yl[4 * H_];
  int h = blockIdx.x, bg = blockIdx.y, tid = threadIdx.x;
  #pragma unroll
  for (int k = 0; k < 4; ++k) {
    int idx4 = k * 256 + tid;
    int bl = idx4 >> 8, col4 = idx4 & 255;
    *(float4*)&yl[bl * H_ + col4 * 4] =
        *(const float4*)(y2 + ((size_t)((bg * 4 + bl) * NH_ + h)) * H_ + col4 * 4);
  }
  __syncthreads();
  int d = tid >> 2, p = tid & 3;
  const float* w = Wv + ((size_t)(h * DK_ + d)) * H_ + p * 256;
  float acc[4] = {0.f, 0.f, 0.f, 0.f};
  #pragma unroll 4
  for (int jj = 0; jj < 256; jj += 4) {
    float4 wv = *(const float4*)(w + jj);
    #pragma unroll
    for (int bl = 0; bl < 4; ++bl) {
      float4 yv = *(const float4*)&yl[bl * H_ + p * 256 + jj];
      acc[bl] += DOT4(yv, wv);
    }
  }
  #pragma unroll
  for (int bl = 0; bl < 4; ++bl) {
    acc[bl] += __shfl_xor(acc[bl], 1);
    acc[bl] += __shfl_xor(acc[bl], 2);
  }
  if (p == 0) {
    float bias = bv[h * DK_ + d];
    #pragma unroll
    for (int bl = 0; bl < 4; ++bl)
      op[(size_t)(bg * 4 + bl) * H_ + h * DK_ + d] = acc[bl] + bias;
  }
}

// -------- kernel 6: out[b,i] = Wo[i,:].out_pre[b,:] + bo[i] ----------------
__global__ __launch_bounds__(256) void k_out(const float* __restrict__ op,
                                             const float* __restrict__ Wo,
                                             const float* __restrict__ bo,
                                             float* __restrict__ out) {
  __shared__ __align__(16) float ul[4 * H_];
  int islab = blockIdx.x, bg = blockIdx.y, tid = threadIdx.x;
  #pragma unroll
  for (int k = 0; k < 4; ++k) {
    int idx4 = k * 256 + tid;
    int bl = idx4 >> 8, col4 = idx4 & 255;
    *(float4*)&ul[bl * H_ + col4 * 4] =
        *(const float4*)(op + (size_t)(bg * 4 + bl) * H_ + col4 * 4);
  }
  __syncthreads();
  int d = tid >> 2, p = tid & 3;
  int i = islab * 64 + d;
  const float* w = Wo + (size_t)i * H_ + p * 256;
  float acc[4] = {0.f, 0.f, 0.f, 0.f};
  #pragma unroll 4
  for (int jj = 0; jj < 256; jj += 4) {
    float4 wv = *(const float4*)(w + jj);
    #pragma unroll
    for (int bl = 0; bl < 4; ++bl) {
      float4 uv = *(const float4*)&ul[bl * H_ + p * 256 + jj];
      acc[bl] += DOT4(uv, wv);
    }
  }
  #pragma unroll
  for (int bl = 0; bl < 4; ++bl) {
    acc[bl] += __shfl_xor(acc[bl], 1);
    acc[bl] += __shfl_xor(acc[bl], 2);
  }
  if (p == 0) {
    float bias = bo[i];
    #pragma unroll
    for (int bl = 0; bl < 4; ++bl)
      out[(size_t)(bg * 4 + bl) * H_ + i] = acc[bl] + bias;
  }
}

extern "C" void kernel_launch(void* const* d_in, const int* in_sizes, int n_in,
                              void* d_out, int out_size, void* d_ws, size_t ws_size,
                              hipStream_t stream) {
  const float* x  = (const float*)d_in[0];
  const float* Wq = (const float*)d_in[1];
  const float* bq = (const float*)d_in[2];
  const float* Wk = (const float*)d_in[3];
  const float* Wv = (const float*)d_in[5];
  const float* bv = (const float*)d_in[6];
  const float* Wo = (const float*)d_in[7];
  const float* bo = (const float*)d_in[8];
  float* out = (float*)d_out;
  float* ws = (float*)d_ws;

  float* q  = ws + Q_OFF;
  float* t  = ws + T_OFF;
  float* yp = ws + YP_OFF;
  float* ml = ws + ML_OFF;
  float* y2 = ws + Y2_OFF;
  float* op = ws + OP_OFF;

  k_q<<<dim3(16, B_ / 4), 256, 0, stream>>>(x, Wq, bq, q);
  k_t<<<dim3(8, NH_), 256, 0, stream>>>(q, Wk, t);
  k_flash<<<dim3(NCH, B_), 256, 0, stream>>>(x, t, yp, ml);
  k_yred<<<dim3(NH_, B_), 256, 0, stream>>>(yp, ml, y2);
  k_vproj<<<dim3(NH_, B_ / 4), 256, 0, stream>>>(y2, Wv, bv, op);
  k_out<<<dim3(16, B_ / 4), 256, 0, stream>>>(op, Wo, bo, out);
}